// Round 3
// baseline (333.701 us; speedup 1.0000x reference)
//
#include <hip/hip_runtime.h>
#include <hip/hip_bf16.h>
#include <math.h>

typedef __attribute__((ext_vector_type(8))) short bf16x8;
typedef __attribute__((ext_vector_type(4))) float f32x4;

typedef const __attribute__((address_space(1))) unsigned int guint;
typedef __attribute__((address_space(3))) unsigned int luint;

static __device__ __forceinline__ short f2bf(float f) {
    union { float f; unsigned u; } a; a.f = f;
    unsigned r = 0x7FFFu + ((a.u >> 16) & 1u);
    return (short)((a.u + r) >> 16);
}
static __device__ __forceinline__ float bf2f(short s) {
    union { unsigned u; float f; } a;
    a.u = ((unsigned)(unsigned short)s) << 16;
    return a.f;
}

// ---------------------------------------------------------------------------
// Weight transpose: W (c,d) fp32 -> WT (d,c) bf16 * scale, 4 weights in z.
// z=0 (Wq) gets qscale folded in; WqT and WkT are adjacent -> WqkT (1024,512).
// ---------------------------------------------------------------------------
__global__ __launch_bounds__(256)
void transpose_w(const float* __restrict__ w0, const float* __restrict__ w1,
                 const float* __restrict__ w2, const float* __restrict__ w3,
                 short* __restrict__ outT, float qscale)
{
    __shared__ float ld[32][33];
    const float* W = (blockIdx.z == 0) ? w0 : (blockIdx.z == 1) ? w1
                   : (blockIdx.z == 2) ? w2 : w3;
    const float sc = (blockIdx.z == 0) ? qscale : 1.f;
    short* O = outT + (long long)blockIdx.z * 512 * 512;
    const int tx = threadIdx.x & 31, ty = threadIdx.x >> 5;
    const int c0 = blockIdx.y * 32, d0 = blockIdx.x * 32;
#pragma unroll
    for (int r = 0; r < 4; ++r)
        ld[ty + 8 * r][tx] = W[(long long)(c0 + ty + 8 * r) * 512 + d0 + tx];
    __syncthreads();
#pragma unroll
    for (int r = 0; r < 4; ++r)
        O[(long long)(d0 + ty + 8 * r) * 512 + c0 + tx] = f2bf(ld[tx][ty + 8 * r] * sc);
}

__global__ __launch_bounds__(256)
void concat_bias(const float* __restrict__ bq, const float* __restrict__ bk,
                 float* __restrict__ bqk, float qscale)
{
    int i = blockIdx.x * 256 + threadIdx.x;  // grid 4
    bqk[i] = (i < 512) ? bq[i] * qscale : bk[i - 512];
}

// ---------------------------------------------------------------------------
// GroupNorm stats: one block per (b,g); group = 16 ch x 1024 spatial.
// ---------------------------------------------------------------------------
__global__ __launch_bounds__(256)
void gn_stats(const float* __restrict__ x, float2* __restrict__ stats)
{
    const int bg = blockIdx.x;
    const float4* p = reinterpret_cast<const float4*>(x + (long long)bg * 16384);
    float s = 0.f, ss = 0.f;
    for (int i = threadIdx.x; i < 4096; i += 256) {
        float4 v = p[i];
        s  += v.x + v.y + v.z + v.w;
        ss += v.x * v.x + v.y * v.y + v.z * v.z + v.w * v.w;
    }
    __shared__ float rs[256], rss[256];
    rs[threadIdx.x] = s; rss[threadIdx.x] = ss;
    __syncthreads();
    for (int o = 128; o > 0; o >>= 1) {
        if (threadIdx.x < o) { rs[threadIdx.x] += rs[threadIdx.x + o];
                               rss[threadIdx.x] += rss[threadIdx.x + o]; }
        __syncthreads();
    }
    if (threadIdx.x == 0) {
        float mean = rs[0] * (1.f / 16384.f);
        float var  = rss[0] * (1.f / 16384.f) - mean * mean;
        stats[bg] = make_float2(mean, rsqrtf(var + 1e-6f));
    }
}

// ---------------------------------------------------------------------------
// GroupNorm apply + transpose: x (b,c,s) fp32 -> hn (b,s,c) bf16.
// ---------------------------------------------------------------------------
__global__ __launch_bounds__(256)
void gn_apply_t(const float* __restrict__ x, const float2* __restrict__ stats,
                const float* __restrict__ gamma, const float* __restrict__ beta,
                short* __restrict__ hn)
{
    __shared__ short lds[32 * 520];
    const int t = threadIdx.x;
    const int s0 = blockIdx.x * 32;
    const int b  = blockIdx.y;
#pragma unroll
    for (int i = 0; i < 16; ++i) {
        int qi = t + 256 * i;
        int c = qi >> 3, sc = qi & 7;
        float4 v = *reinterpret_cast<const float4*>(
            x + ((long long)(b * 512 + c)) * 1024 + s0 + sc * 4);
        float2 st = stats[b * 32 + (c >> 4)];
        float ga = gamma[c], be = beta[c];
        float m = st.x, r = st.y;
        lds[(sc * 4 + 0) * 520 + c] = f2bf((v.x - m) * r * ga + be);
        lds[(sc * 4 + 1) * 520 + c] = f2bf((v.y - m) * r * ga + be);
        lds[(sc * 4 + 2) * 520 + c] = f2bf((v.z - m) * r * ga + be);
        lds[(sc * 4 + 3) * 520 + c] = f2bf((v.w - m) * r * ga + be);
    }
    __syncthreads();
#pragma unroll
    for (int i = 0; i < 8; ++i) {
        int p = t + 256 * i;
        int s = p >> 6, j = p & 63;
        float4 v = *reinterpret_cast<const float4*>(&lds[s * 520 + j * 8]);
        *reinterpret_cast<float4*>(
            hn + ((long long)(b * 1024 + s0 + s)) * 512 + j * 8) = v;
    }
}

// ---------------------------------------------------------------------------
// NT GEMM, 2-phase double-buffered (T3-minimal): stage next K-tile via
// global_load_lds(16B) into buf^1, ds_read+MFMA from buf, ONE
// __syncthreads per K-tile (its vmcnt(0) lands after the MFMAs, so the
// staging latency hides under compute). 128x128 tile, 4 waves, 16x16x32.
// XCD-aware 1-D grid remap keeps each batch's panels on one XCD's L2.
// C[m,n] = f(sum_k A[m,k]*B[n,k] + biasM[m] + biasN[n]) with optional
// exp(v-8) (EXPOUT), row divide (DIVROW), fp32 residual add (RESID).
// ---------------------------------------------------------------------------
template<int BIAS_M, int BIAS_N, int RESID, int EXPOUT, int DIVROW>
__global__ __launch_bounds__(256)
void nt_gemm(const short* __restrict__ A, const short* __restrict__ B,
             void* __restrict__ Cv,
             const float* __restrict__ biasM, const float* __restrict__ biasN,
             const float* __restrict__ resid, const float* __restrict__ rs,
             int rsM, float scale, int K, int lda, int ldb, int ldc,
             long long sA, long long sB, long long sC,
             int tilesM, int tilesPerBatch)
{
    __shared__ short lsA[2][128 * 64];   // 2 x 16 KB per operand (64 KB total)
    __shared__ short lsB[2][128 * 64];

    const int id = blockIdx.x;
    const int chunk = gridDim.x >> 3;    // grid % 8 == 0 by construction
    const int gid = (id & 7) * chunk + (id >> 3);
    const int bz = gid / tilesPerBatch;
    const int tt = gid - bz * tilesPerBatch;
    const int m0 = (tt % tilesM) * 128;
    const int n0 = (tt / tilesM) * 128;

    const int t = threadIdx.x;
    const int lane = t & 63;
    const int w = t >> 6;
    const int wr = w >> 1, wc = w & 1;
    const int lr16 = lane & 15, lkg = lane >> 4;

    const int srow = 32 * w + (lane >> 3);
    const int scol = (lane & 7) * 8;
    const short* gA = A + (long long)bz * sA + (long long)(m0 + srow) * lda + scol;
    const short* gB = B + (long long)bz * sB + (long long)(n0 + srow) * ldb + scol;

    f32x4 acc[4][4];
#pragma unroll
    for (int i = 0; i < 4; ++i)
#pragma unroll
        for (int j = 0; j < 4; ++j) acc[i][j] = (f32x4){0.f, 0.f, 0.f, 0.f};

    const int nk = K >> 6;

#define STAGE(buf, kt)                                                         \
    {                                                                          \
        const short* ga_ = gA + (kt) * 64;                                     \
        const short* gb_ = gB + (kt) * 64;                                     \
        _Pragma("unroll")                                                      \
        for (int c = 0; c < 4; ++c) {                                          \
            __builtin_amdgcn_global_load_lds(                                  \
                (guint*)(ga_ + (long long)(8 * c) * lda),                      \
                (luint*)&lsA[buf][(32 * w + 8 * c) * 64], 16, 0, 0);           \
            __builtin_amdgcn_global_load_lds(                                  \
                (guint*)(gb_ + (long long)(8 * c) * ldb),                      \
                (luint*)&lsB[buf][(32 * w + 8 * c) * 64], 16, 0, 0);           \
        }                                                                      \
    }

#define COMPUTE(buf)                                                           \
    {                                                                          \
        _Pragma("unroll")                                                      \
        for (int ks = 0; ks < 2; ++ks) {                                       \
            bf16x8 af[4], bfr[4];                                              \
            _Pragma("unroll")                                                  \
            for (int mi = 0; mi < 4; ++mi)                                     \
                af[mi] = *reinterpret_cast<const bf16x8*>(                     \
                    &lsA[buf][(wr * 64 + mi * 16 + lr16) * 64 + ks * 32 + lkg * 8]); \
            _Pragma("unroll")                                                  \
            for (int ni = 0; ni < 4; ++ni)                                     \
                bfr[ni] = *reinterpret_cast<const bf16x8*>(                    \
                    &lsB[buf][(wc * 64 + ni * 16 + lr16) * 64 + ks * 32 + lkg * 8]); \
            _Pragma("unroll")                                                  \
            for (int mi = 0; mi < 4; ++mi)                                     \
                _Pragma("unroll")                                              \
                for (int ni = 0; ni < 4; ++ni)                                 \
                    acc[mi][ni] = __builtin_amdgcn_mfma_f32_16x16x32_bf16(     \
                        af[mi], bfr[ni], acc[mi][ni], 0, 0, 0);                \
        }                                                                      \
    }

    STAGE(0, 0);
    __syncthreads();                      // prologue drain (vmcnt0 + barrier)
    int cur = 0;
    for (int kt = 0; kt < nk - 1; ++kt) {
        STAGE(cur ^ 1, kt + 1);           // issue next-tile loads first
        COMPUTE(cur);                     // MFMAs overlap the loads
        __syncthreads();                  // single drain+barrier per K-tile
        cur ^= 1;
    }
    COMPUTE(cur);
#undef STAGE
#undef COMPUTE

    // epilogue: D layout col=lane&15, row=(lane>>4)*4+reg (m89-verified)
#pragma unroll
    for (int mi = 0; mi < 4; ++mi) {
        float addm[4], mul[4];
#pragma unroll
        for (int j = 0; j < 4; ++j) {
            const int rrow = m0 + wr * 64 + mi * 16 + lkg * 4 + j;
            addm[j] = BIAS_M ? biasM[rrow] : 0.f;
            mul[j]  = DIVROW ? 1.f / rs[(long long)bz * rsM + rrow] : 1.f;
        }
#pragma unroll
        for (int ni = 0; ni < 4; ++ni) {
            const int col = n0 + wc * 64 + ni * 16 + lr16;
            float bn = BIAS_N ? biasN[col] : 0.f;
#pragma unroll
            for (int j = 0; j < 4; ++j) {
                const int rrow = m0 + wr * 64 + mi * 16 + lkg * 4 + j;
                float v2 = acc[mi][ni][j] + addm[j] + bn;
                v2 *= scale;
                if (EXPOUT) v2 = __expf(v2 - 8.f);
                if (DIVROW) v2 *= mul[j];
                const long long idx = (long long)rrow * ldc + col;
                if (RESID) {
                    float* Cf = (float*)Cv + (long long)bz * sC;
                    Cf[idx] = v2 + resid[(long long)bz * sC + idx];
                } else {
                    short* Cs = (short*)Cv + (long long)bz * sC;
                    Cs[idx] = f2bf(v2);
                }
            }
        }
    }
}

// ---------------------------------------------------------------------------
// Row sums of expS (bf16, rows of 1024): one wave per row, read-only + tiny
// write. Replaces the full softmax r/w pass (PV epilogue divides by rs).
// ---------------------------------------------------------------------------
__global__ __launch_bounds__(256)
void rowsum_rows(const short* __restrict__ S, float* __restrict__ rs)
{
    const int wave = threadIdx.x >> 6, lane = threadIdx.x & 63;
    const long long row = (long long)blockIdx.x * 4 + wave;
    const short* p = S + row * 1024;
    bf16x8 h0 = *reinterpret_cast<const bf16x8*>(p + lane * 8);
    bf16x8 h1 = *reinterpret_cast<const bf16x8*>(p + 512 + lane * 8);
    float s = 0.f;
#pragma unroll
    for (int j = 0; j < 8; ++j) s += bf2f(h0[j]) + bf2f(h1[j]);
#pragma unroll
    for (int o = 32; o > 0; o >>= 1) s += __shfl_xor(s, o);
    if (lane == 0) rs[row] = s;
}

// ---------------------------------------------------------------------------
extern "C" void kernel_launch(void* const* d_in, const int* in_sizes, int n_in,
                              void* d_out, int out_size, void* d_ws, size_t ws_size,
                              hipStream_t stream)
{
    (void)in_sizes; (void)n_in; (void)out_size; (void)ws_size;
    const float* x     = (const float*)d_in[0];
    const float* gamma = (const float*)d_in[1];
    const float* beta  = (const float*)d_in[2];
    const float* Wq = (const float*)d_in[3];
    const float* bq = (const float*)d_in[4];
    const float* Wk = (const float*)d_in[5];
    const float* bk = (const float*)d_in[6];
    const float* Wv = (const float*)d_in[7];
    const float* bv = (const float*)d_in[8];
    const float* Wp = (const float*)d_in[9];
    const float* bp = (const float*)d_in[10];
    float* out = (float*)d_out;

    // Workspace (time-overlapped), ~162.2 MB:
    //   [0,64M):    expS (b,s,t) bf16; hn (b,s,c) bf16 in [0,32M) dies after
    //               the v-GEMM, before scores writes expS.
    //   [64,128M):  qk (b,s,1024) bf16 (q cols 0-511, k cols 512-1023);
    //               dies after scores; ho (b,s,c) reuses [64,96M).
    //   [128,160M): v (b,c,t) bf16
    //   [160,162M): WT = {WqT*qs, WkT, WvT, WpT} (d,c) bf16
    //   [162M..):   stats (8K) | bqk (4K) | rs (128K)
    char* ws = (char*)d_ws;
    short*  expS = (short*)ws;
    short*  hn   = (short*)ws;
    short*  qkb  = (short*)(ws + (64LL << 20));
    short*  vbuf = (short*)(ws + (128LL << 20));
    short*  wT   = (short*)(ws + (160LL << 20));
    float2* stats = (float2*)(ws + (162LL << 20));
    float*  bqk   = (float*)(ws + (162LL << 20) + (16 << 10));
    float*  rs    = (float*)(ws + (162LL << 20) + (32 << 10));
    short*  ho    = qkb;

    const short* WqkT = wT;                    // rows 0-511: Wq^T*qs; 512-1023: Wk^T
    const short* WvT  = wT + 2 * 512 * 512;
    const short* WpT  = wT + 3 * 512 * 512;

    const float qscale = 0.044194173824159216f;  // 512^-0.5

    transpose_w<<<dim3(16, 16, 4), 256, 0, stream>>>(Wq, Wk, Wv, Wp, wT, qscale);
    concat_bias<<<dim3(4), 256, 0, stream>>>(bq, bk, bqk, qscale);
    gn_stats<<<dim3(1024), 256, 0, stream>>>(x, stats);
    gn_apply_t<<<dim3(32, 32), 256, 0, stream>>>(x, stats, gamma, beta, hn);

    // qk = hn @ [Wq*qs | Wk] + bqk : M=1024(s), N=1024(d'), K=512
    nt_gemm<0, 1, 0, 0, 0><<<2048, 256, 0, stream>>>(
        hn, WqkT, qkb, nullptr, bqk, nullptr, nullptr, 0, 1.f,
        512, 512, 512, 1024, 1024 * 512, 0, 1024LL * 1024, 8, 64);
    // v (d,t) = WvT @ hn^T + bv : M=512(d), N=1024(t), K=512
    nt_gemm<1, 0, 0, 0, 0><<<1024, 256, 0, stream>>>(
        WvT, hn, vbuf, bv, nullptr, nullptr, nullptr, 0, 1.f,
        512, 512, 512, 1024, 0, 1024 * 512, 512 * 1024, 4, 32);
    // expS (s,t) = exp(q @ k^T - 8) : M=N=1024, K=512 (qscale folded into q)
    nt_gemm<0, 0, 0, 1, 0><<<2048, 256, 0, stream>>>(
        qkb, qkb + 512, expS, nullptr, nullptr, nullptr, nullptr, 0, 1.f,
        512, 1024, 1024, 1024, 1024LL * 1024, 1024LL * 1024, 1024LL * 1024, 8, 64);
    // rs[row] = sum_t expS
    rowsum_rows<<<dim3(8192), 256, 0, stream>>>(expS, rs);
    // ho (s,c) = (expS @ v^T) / rs : M=1024(s), N=512(c), K=1024
    nt_gemm<0, 0, 0, 0, 1><<<1024, 256, 0, stream>>>(
        expS, vbuf, ho, nullptr, nullptr, nullptr, rs, 1024, 1.f,
        1024, 1024, 1024, 512, 1024LL * 1024, 512 * 1024, 1024 * 512, 8, 32);
    // out (d,s) = WpT @ ho^T + bp + x : M=512(d), N=1024(s), K=512, fp32
    nt_gemm<1, 0, 1, 0, 0><<<1024, 256, 0, stream>>>(
        WpT, ho, out, bp, nullptr, x, nullptr, 0, 1.f,
        512, 512, 512, 1024, 0, 1024 * 512, 512LL * 1024, 4, 32);
}

// Round 4
// 251.747 us; speedup vs baseline: 1.3255x; 1.3255x over previous
//
#include <hip/hip_runtime.h>
#include <hip/hip_bf16.h>
#include <math.h>

typedef __attribute__((ext_vector_type(8))) short bf16x8;
typedef __attribute__((ext_vector_type(4))) float f32x4;

typedef const __attribute__((address_space(1))) unsigned int guint;
typedef __attribute__((address_space(3))) unsigned int luint;

static __device__ __forceinline__ short f2bf(float f) {
    union { float f; unsigned u; } a; a.f = f;
    unsigned r = 0x7FFFu + ((a.u >> 16) & 1u);
    return (short)((a.u + r) >> 16);
}
static __device__ __forceinline__ float bf2f(short s) {
    union { unsigned u; float f; } a;
    a.u = ((unsigned)(unsigned short)s) << 16;
    return a.f;
}

// ---------------------------------------------------------------------------
// Weight transpose: W (c,d) fp32 -> WT (d,c) bf16 * scale, 4 weights in z.
// z=0 (Wq) gets qscale folded in; WqT and WkT adjacent -> WqkT (1024,512).
// ---------------------------------------------------------------------------
__global__ __launch_bounds__(256)
void transpose_w(const float* __restrict__ w0, const float* __restrict__ w1,
                 const float* __restrict__ w2, const float* __restrict__ w3,
                 short* __restrict__ outT, float qscale)
{
    __shared__ float ld[32][33];
    const float* W = (blockIdx.z == 0) ? w0 : (blockIdx.z == 1) ? w1
                   : (blockIdx.z == 2) ? w2 : w3;
    const float sc = (blockIdx.z == 0) ? qscale : 1.f;
    short* O = outT + (long long)blockIdx.z * 512 * 512;
    const int tx = threadIdx.x & 31, ty = threadIdx.x >> 5;
    const int c0 = blockIdx.y * 32, d0 = blockIdx.x * 32;
#pragma unroll
    for (int r = 0; r < 4; ++r)
        ld[ty + 8 * r][tx] = W[(long long)(c0 + ty + 8 * r) * 512 + d0 + tx];
    __syncthreads();
#pragma unroll
    for (int r = 0; r < 4; ++r)
        O[(long long)(d0 + ty + 8 * r) * 512 + c0 + tx] = f2bf(ld[tx][ty + 8 * r] * sc);
}

__global__ __launch_bounds__(256)
void concat_bias(const float* __restrict__ bq, const float* __restrict__ bk,
                 float* __restrict__ bqk, float qscale)
{
    int i = blockIdx.x * 256 + threadIdx.x;  // grid 4
    bqk[i] = (i < 512) ? bq[i] * qscale : bk[i - 512];
}

// ---------------------------------------------------------------------------
// GroupNorm stats: one block per (b,g); group = 16 ch x 1024 spatial.
// ---------------------------------------------------------------------------
__global__ __launch_bounds__(256)
void gn_stats(const float* __restrict__ x, float2* __restrict__ stats)
{
    const int bg = blockIdx.x;
    const float4* p = reinterpret_cast<const float4*>(x + (long long)bg * 16384);
    float s = 0.f, ss = 0.f;
    for (int i = threadIdx.x; i < 4096; i += 256) {
        float4 v = p[i];
        s  += v.x + v.y + v.z + v.w;
        ss += v.x * v.x + v.y * v.y + v.z * v.z + v.w * v.w;
    }
    __shared__ float rs[256], rss[256];
    rs[threadIdx.x] = s; rss[threadIdx.x] = ss;
    __syncthreads();
    for (int o = 128; o > 0; o >>= 1) {
        if (threadIdx.x < o) { rs[threadIdx.x] += rs[threadIdx.x + o];
                               rss[threadIdx.x] += rss[threadIdx.x + o]; }
        __syncthreads();
    }
    if (threadIdx.x == 0) {
        float mean = rs[0] * (1.f / 16384.f);
        float var  = rss[0] * (1.f / 16384.f) - mean * mean;
        stats[bg] = make_float2(mean, rsqrtf(var + 1e-6f));
    }
}

// ---------------------------------------------------------------------------
// GroupNorm apply + transpose: x (b,c,s) fp32 -> hn (b,s,c) bf16.
// ---------------------------------------------------------------------------
__global__ __launch_bounds__(256)
void gn_apply_t(const float* __restrict__ x, const float2* __restrict__ stats,
                const float* __restrict__ gamma, const float* __restrict__ beta,
                short* __restrict__ hn)
{
    __shared__ short lds[32 * 520];
    const int t = threadIdx.x;
    const int s0 = blockIdx.x * 32;
    const int b  = blockIdx.y;
#pragma unroll
    for (int i = 0; i < 16; ++i) {
        int qi = t + 256 * i;
        int c = qi >> 3, sc = qi & 7;
        float4 v = *reinterpret_cast<const float4*>(
            x + ((long long)(b * 512 + c)) * 1024 + s0 + sc * 4);
        float2 st = stats[b * 32 + (c >> 4)];
        float ga = gamma[c], be = beta[c];
        float m = st.x, r = st.y;
        lds[(sc * 4 + 0) * 520 + c] = f2bf((v.x - m) * r * ga + be);
        lds[(sc * 4 + 1) * 520 + c] = f2bf((v.y - m) * r * ga + be);
        lds[(sc * 4 + 2) * 520 + c] = f2bf((v.z - m) * r * ga + be);
        lds[(sc * 4 + 3) * 520 + c] = f2bf((v.w - m) * r * ga + be);
    }
    __syncthreads();
#pragma unroll
    for (int i = 0; i < 8; ++i) {
        int p = t + 256 * i;
        int s = p >> 6, j = p & 63;
        float4 v = *reinterpret_cast<const float4*>(&lds[s * 520 + j * 8]);
        *reinterpret_cast<float4*>(
            hn + ((long long)(b * 1024 + s0 + s)) * 512 + j * 8) = v;
    }
}

// ---------------------------------------------------------------------------
// NT GEMM, counted-vmcnt pipeline (T4) + both-sides XOR swizzle (T2/rule21):
//   iter kt: STAGE(kt+1 -> buf^1) ; s_waitcnt vmcnt(8) (tile kt complete,
//   tile kt+1's 8 loads stay IN FLIGHT across the raw s_barrier) ; compute.
// LDS swizzle: gload_lds dest is lane-linear, so the global SOURCE col-chunk
// is pre-swizzled (chunk = (l&7) ^ ((l>>3)&7)) and ds_read applies the same
// XOR (chunk ^ (row&7)) -> 16-way read conflict becomes 2-way (free).
// 128x128 tile, BK=64, 4 waves, 16x16x32 MFMA. XCD-aware 1-D grid remap.
// C[m,n] = f(sum_k A[m,k]*B[n,k] + biasM[m] + biasN[n]) with optional
// exp(v-8) (EXPOUT), row divide (DIVROW), fp32 residual add (RESID).
// ---------------------------------------------------------------------------
template<int BIAS_M, int BIAS_N, int RESID, int EXPOUT, int DIVROW>
__global__ __launch_bounds__(256)
void nt_gemm(const short* __restrict__ A, const short* __restrict__ B,
             void* __restrict__ Cv,
             const float* __restrict__ biasM, const float* __restrict__ biasN,
             const float* __restrict__ resid, const float* __restrict__ rs,
             int rsM, float scale, int K, int lda, int ldb, int ldc,
             long long sA, long long sB, long long sC,
             int tilesM, int tilesPerBatch)
{
    __shared__ short lsA[2][128 * 64];   // 2 x 16 KB per operand (64 KB total)
    __shared__ short lsB[2][128 * 64];

    const int id = blockIdx.x;
    const int chunk = gridDim.x >> 3;    // grid % 8 == 0 by construction
    const int gid = (id & 7) * chunk + (id >> 3);
    const int bz = gid / tilesPerBatch;
    const int tt = gid - bz * tilesPerBatch;
    const int m0 = (tt % tilesM) * 128;
    const int n0 = (tt / tilesM) * 128;

    const int t = threadIdx.x;
    const int lane = t & 63;
    const int w = t >> 6;
    const int wr = w >> 1, wc = w & 1;
    const int lr16 = lane & 15, lkg = lane >> 4;
    const int sw = lr16 & 7;             // read-side swizzle key

    // staging: lane l -> row 32w + l/8, SWIZZLED global col chunk
    const int srow = 32 * w + (lane >> 3);
    const int scol = (((lane & 7) ^ ((lane >> 3) & 7))) * 8;
    const short* gA = A + (long long)bz * sA + (long long)(m0 + srow) * lda + scol;
    const short* gB = B + (long long)bz * sB + (long long)(n0 + srow) * ldb + scol;

    f32x4 acc[4][4];
#pragma unroll
    for (int i = 0; i < 4; ++i)
#pragma unroll
        for (int j = 0; j < 4; ++j) acc[i][j] = (f32x4){0.f, 0.f, 0.f, 0.f};

    const int nk = K >> 6;

#define STAGE(buf, kt)                                                         \
    {                                                                          \
        const short* ga_ = gA + (kt) * 64;                                     \
        const short* gb_ = gB + (kt) * 64;                                     \
        _Pragma("unroll")                                                      \
        for (int c = 0; c < 4; ++c) {                                          \
            __builtin_amdgcn_global_load_lds(                                  \
                (guint*)(ga_ + (long long)(8 * c) * lda),                      \
                (luint*)&lsA[buf][(32 * w + 8 * c) * 64], 16, 0, 0);           \
            __builtin_amdgcn_global_load_lds(                                  \
                (guint*)(gb_ + (long long)(8 * c) * ldb),                      \
                (luint*)&lsB[buf][(32 * w + 8 * c) * 64], 16, 0, 0);           \
        }                                                                      \
    }

#define COMPUTE(buf)                                                           \
    {                                                                          \
        _Pragma("unroll")                                                      \
        for (int ks = 0; ks < 2; ++ks) {                                       \
            bf16x8 af[4], bfr[4];                                              \
            _Pragma("unroll")                                                  \
            for (int mi = 0; mi < 4; ++mi)                                     \
                af[mi] = *reinterpret_cast<const bf16x8*>(                     \
                    &lsA[buf][(wr * 64 + mi * 16 + lr16) * 64 +                \
                              (((ks * 4 + lkg) ^ sw) * 8)]);                   \
            _Pragma("unroll")                                                  \
            for (int ni = 0; ni < 4; ++ni)                                     \
                bfr[ni] = *reinterpret_cast<const bf16x8*>(                    \
                    &lsB[buf][(wc * 64 + ni * 16 + lr16) * 64 +                \
                              (((ks * 4 + lkg) ^ sw) * 8)]);                   \
            __builtin_amdgcn_s_setprio(1);                                     \
            _Pragma("unroll")                                                  \
            for (int mi = 0; mi < 4; ++mi)                                     \
                _Pragma("unroll")                                              \
                for (int ni = 0; ni < 4; ++ni)                                 \
                    acc[mi][ni] = __builtin_amdgcn_mfma_f32_16x16x32_bf16(     \
                        af[mi], bfr[ni], acc[mi][ni], 0, 0, 0);                \
            __builtin_amdgcn_s_setprio(0);                                     \
        }                                                                      \
    }

    STAGE(0, 0);
    int cur = 0;
    for (int kt = 0; kt < nk - 1; ++kt) {
        STAGE(cur ^ 1, kt + 1);
        asm volatile("s_waitcnt vmcnt(8)" ::: "memory");  // tile kt done; kt+1 in flight
        __builtin_amdgcn_sched_barrier(0);
        __builtin_amdgcn_s_barrier();
        __builtin_amdgcn_sched_barrier(0);
        COMPUTE(cur);
        __builtin_amdgcn_sched_barrier(0);
        __builtin_amdgcn_s_barrier();                     // reads done before overwrite
        __builtin_amdgcn_sched_barrier(0);
        cur ^= 1;
    }
    asm volatile("s_waitcnt vmcnt(0)" ::: "memory");      // drain last tile
    __builtin_amdgcn_sched_barrier(0);
    __builtin_amdgcn_s_barrier();
    __builtin_amdgcn_sched_barrier(0);
    COMPUTE(cur);
#undef STAGE
#undef COMPUTE

    // epilogue: D layout col=lane&15, row=(lane>>4)*4+reg (m89-verified)
#pragma unroll
    for (int mi = 0; mi < 4; ++mi) {
        float addm[4], mul[4];
#pragma unroll
        for (int j = 0; j < 4; ++j) {
            const int rrow = m0 + wr * 64 + mi * 16 + lkg * 4 + j;
            addm[j] = BIAS_M ? biasM[rrow] : 0.f;
            mul[j]  = DIVROW ? 1.f / rs[(long long)bz * rsM + rrow] : 1.f;
        }
#pragma unroll
        for (int ni = 0; ni < 4; ++ni) {
            const int col = n0 + wc * 64 + ni * 16 + lr16;
            float bn = BIAS_N ? biasN[col] : 0.f;
#pragma unroll
            for (int j = 0; j < 4; ++j) {
                const int rrow = m0 + wr * 64 + mi * 16 + lkg * 4 + j;
                float v2 = acc[mi][ni][j] + addm[j] + bn;
                v2 *= scale;
                if (EXPOUT) v2 = __expf(v2 - 8.f);
                if (DIVROW) v2 *= mul[j];
                const long long idx = (long long)rrow * ldc + col;
                if (RESID) {
                    float* Cf = (float*)Cv + (long long)bz * sC;
                    Cf[idx] = v2 + resid[(long long)bz * sC + idx];
                } else {
                    short* Cs = (short*)Cv + (long long)bz * sC;
                    Cs[idx] = f2bf(v2);
                }
            }
        }
    }
}

// ---------------------------------------------------------------------------
// Row sums of expS (bf16, rows of 1024): one wave per row.
// ---------------------------------------------------------------------------
__global__ __launch_bounds__(256)
void rowsum_rows(const short* __restrict__ S, float* __restrict__ rs)
{
    const int wave = threadIdx.x >> 6, lane = threadIdx.x & 63;
    const long long row = (long long)blockIdx.x * 4 + wave;
    const short* p = S + row * 1024;
    bf16x8 h0 = *reinterpret_cast<const bf16x8*>(p + lane * 8);
    bf16x8 h1 = *reinterpret_cast<const bf16x8*>(p + 512 + lane * 8);
    float s = 0.f;
#pragma unroll
    for (int j = 0; j < 8; ++j) s += bf2f(h0[j]) + bf2f(h1[j]);
#pragma unroll
    for (int o = 32; o > 0; o >>= 1) s += __shfl_xor(s, o);
    if (lane == 0) rs[row] = s;
}

// ---------------------------------------------------------------------------
extern "C" void kernel_launch(void* const* d_in, const int* in_sizes, int n_in,
                              void* d_out, int out_size, void* d_ws, size_t ws_size,
                              hipStream_t stream)
{
    (void)in_sizes; (void)n_in; (void)out_size; (void)ws_size;
    const float* x     = (const float*)d_in[0];
    const float* gamma = (const float*)d_in[1];
    const float* beta  = (const float*)d_in[2];
    const float* Wq = (const float*)d_in[3];
    const float* bq = (const float*)d_in[4];
    const float* Wk = (const float*)d_in[5];
    const float* bk = (const float*)d_in[6];
    const float* Wv = (const float*)d_in[7];
    const float* bv = (const float*)d_in[8];
    const float* Wp = (const float*)d_in[9];
    const float* bp = (const float*)d_in[10];
    float* out = (float*)d_out;

    // Workspace (time-overlapped), ~162.2 MB:
    //   [0,64M):    expS (b,s,t) bf16; hn (b,s,c) bf16 in [0,32M) dies after
    //               the v-GEMM, before scores writes expS.
    //   [64,128M):  qk (b,s,1024) bf16; dies after scores; ho reuses [64,96M).
    //   [128,160M): v (b,c,t) bf16
    //   [160,162M): WT = {WqT*qs, WkT, WvT, WpT} (d,c) bf16
    //   [162M..):   stats (8K) | bqk (4K) | rs (128K)
    char* ws = (char*)d_ws;
    short*  expS = (short*)ws;
    short*  hn   = (short*)ws;
    short*  qkb  = (short*)(ws + (64LL << 20));
    short*  vbuf = (short*)(ws + (128LL << 20));
    short*  wT   = (short*)(ws + (160LL << 20));
    float2* stats = (float2*)(ws + (162LL << 20));
    float*  bqk   = (float*)(ws + (162LL << 20) + (16 << 10));
    float*  rs    = (float*)(ws + (162LL << 20) + (32 << 10));
    short*  ho    = qkb;

    const short* WqkT = wT;                  // rows 0-511: Wq^T*qs; 512-1023: Wk^T
    const short* WvT  = wT + 2 * 512 * 512;
    const short* WpT  = wT + 3 * 512 * 512;

    const float qscale = 0.044194173824159216f;  // 512^-0.5

    transpose_w<<<dim3(16, 16, 4), 256, 0, stream>>>(Wq, Wk, Wv, Wp, wT, qscale);
    concat_bias<<<dim3(4), 256, 0, stream>>>(bq, bk, bqk, qscale);
    gn_stats<<<dim3(1024), 256, 0, stream>>>(x, stats);
    gn_apply_t<<<dim3(32, 32), 256, 0, stream>>>(x, stats, gamma, beta, hn);

    // qk = hn @ [Wq*qs | Wk] + bqk : M=1024(s), N=1024(d'), K=512
    nt_gemm<0, 1, 0, 0, 0><<<2048, 256, 0, stream>>>(
        hn, WqkT, qkb, nullptr, bqk, nullptr, nullptr, 0, 1.f,
        512, 512, 512, 1024, 1024 * 512, 0, 1024LL * 1024, 8, 64);
    // v (d,t) = WvT @ hn^T + bv : M=512(d), N=1024(t), K=512
    nt_gemm<1, 0, 0, 0, 0><<<1024, 256, 0, stream>>>(
        WvT, hn, vbuf, bv, nullptr, nullptr, nullptr, 0, 1.f,
        512, 512, 512, 1024, 0, 1024 * 512, 512 * 1024, 4, 32);
    // expS (s,t) = exp(q @ k^T - 8) : M=N=1024, K=512 (qscale folded into q)
    nt_gemm<0, 0, 0, 1, 0><<<2048, 256, 0, stream>>>(
        qkb, qkb + 512, expS, nullptr, nullptr, nullptr, nullptr, 0, 1.f,
        512, 1024, 1024, 1024, 1024LL * 1024, 1024LL * 1024, 1024LL * 1024, 8, 64);
    // rs[row] = sum_t expS
    rowsum_rows<<<dim3(8192), 256, 0, stream>>>(expS, rs);
    // ho (s,c) = (expS @ v^T) / rs : M=1024(s), N=512(c), K=1024
    nt_gemm<0, 0, 0, 0, 1><<<1024, 256, 0, stream>>>(
        expS, vbuf, ho, nullptr, nullptr, nullptr, rs, 1024, 1.f,
        1024, 1024, 1024, 512, 1024LL * 1024, 512 * 1024, 1024 * 512, 8, 32);
    // out (d,s) = WpT @ ho^T + bp + x : M=512(d), N=1024(s), K=512, fp32
    nt_gemm<1, 0, 1, 0, 0><<<1024, 256, 0, stream>>>(
        WpT, ho, out, bp, nullptr, x, nullptr, 0, 1.f,
        512, 512, 512, 1024, 0, 1024 * 512, 512LL << 10, 4, 32);
}

// Round 5
// 247.247 us; speedup vs baseline: 1.3497x; 1.0182x over previous
//
#include <hip/hip_runtime.h>
#include <hip/hip_bf16.h>
#include <math.h>

typedef __attribute__((ext_vector_type(8))) short bf16x8;
typedef __attribute__((ext_vector_type(4))) float f32x4;

typedef const __attribute__((address_space(1))) unsigned int guint;
typedef __attribute__((address_space(3))) unsigned int luint;

static __device__ __forceinline__ short f2bf(float f) {
    union { float f; unsigned u; } a; a.f = f;
    unsigned r = 0x7FFFu + ((a.u >> 16) & 1u);
    return (short)((a.u + r) >> 16);
}
static __device__ __forceinline__ float bf2f(short s) {
    union { unsigned u; float f; } a;
    a.u = ((unsigned)(unsigned short)s) << 16;
    return a.f;
}

// ---------------------------------------------------------------------------
// Weight transpose: W (c,d) fp32 -> WT (d,c) bf16 * scale, 4 weights in z.
// z=0 (Wq) gets qscale folded in; WqT and WkT adjacent -> WqkT (1024,512).
// ---------------------------------------------------------------------------
__global__ __launch_bounds__(256)
void transpose_w(const float* __restrict__ w0, const float* __restrict__ w1,
                 const float* __restrict__ w2, const float* __restrict__ w3,
                 short* __restrict__ outT, float qscale)
{
    __shared__ float ld[32][33];
    const float* W = (blockIdx.z == 0) ? w0 : (blockIdx.z == 1) ? w1
                   : (blockIdx.z == 2) ? w2 : w3;
    const float sc = (blockIdx.z == 0) ? qscale : 1.f;
    short* O = outT + (long long)blockIdx.z * 512 * 512;
    const int tx = threadIdx.x & 31, ty = threadIdx.x >> 5;
    const int c0 = blockIdx.y * 32, d0 = blockIdx.x * 32;
#pragma unroll
    for (int r = 0; r < 4; ++r)
        ld[ty + 8 * r][tx] = W[(long long)(c0 + ty + 8 * r) * 512 + d0 + tx];
    __syncthreads();
#pragma unroll
    for (int r = 0; r < 4; ++r)
        O[(long long)(d0 + ty + 8 * r) * 512 + c0 + tx] = f2bf(ld[tx][ty + 8 * r] * sc);
}

__global__ __launch_bounds__(256)
void concat_bias(const float* __restrict__ bq, const float* __restrict__ bk,
                 float* __restrict__ bqk, float qscale)
{
    int i = blockIdx.x * 256 + threadIdx.x;  // grid 4
    bqk[i] = (i < 512) ? bq[i] * qscale : bk[i - 512];
}

// ---------------------------------------------------------------------------
// GroupNorm stats: one block per (b,g); group = 16 ch x 1024 spatial.
// ---------------------------------------------------------------------------
__global__ __launch_bounds__(256)
void gn_stats(const float* __restrict__ x, float2* __restrict__ stats)
{
    const int bg = blockIdx.x;
    const float4* p = reinterpret_cast<const float4*>(x + (long long)bg * 16384);
    float s = 0.f, ss = 0.f;
    for (int i = threadIdx.x; i < 4096; i += 256) {
        float4 v = p[i];
        s  += v.x + v.y + v.z + v.w;
        ss += v.x * v.x + v.y * v.y + v.z * v.z + v.w * v.w;
    }
    __shared__ float rs[256], rss[256];
    rs[threadIdx.x] = s; rss[threadIdx.x] = ss;
    __syncthreads();
    for (int o = 128; o > 0; o >>= 1) {
        if (threadIdx.x < o) { rs[threadIdx.x] += rs[threadIdx.x + o];
                               rss[threadIdx.x] += rss[threadIdx.x + o]; }
        __syncthreads();
    }
    if (threadIdx.x == 0) {
        float mean = rs[0] * (1.f / 16384.f);
        float var  = rss[0] * (1.f / 16384.f) - mean * mean;
        stats[bg] = make_float2(mean, rsqrtf(var + 1e-6f));
    }
}

// ---------------------------------------------------------------------------
// GroupNorm apply + transpose: x (b,c,s) fp32 -> hn (b,s,c) bf16.
// ---------------------------------------------------------------------------
__global__ __launch_bounds__(256)
void gn_apply_t(const float* __restrict__ x, const float2* __restrict__ stats,
                const float* __restrict__ gamma, const float* __restrict__ beta,
                short* __restrict__ hn)
{
    __shared__ short lds[32 * 520];
    const int t = threadIdx.x;
    const int s0 = blockIdx.x * 32;
    const int b  = blockIdx.y;
#pragma unroll
    for (int i = 0; i < 16; ++i) {
        int qi = t + 256 * i;
        int c = qi >> 3, sc = qi & 7;
        float4 v = *reinterpret_cast<const float4*>(
            x + ((long long)(b * 512 + c)) * 1024 + s0 + sc * 4);
        float2 st = stats[b * 32 + (c >> 4)];
        float ga = gamma[c], be = beta[c];
        float m = st.x, r = st.y;
        lds[(sc * 4 + 0) * 520 + c] = f2bf((v.x - m) * r * ga + be);
        lds[(sc * 4 + 1) * 520 + c] = f2bf((v.y - m) * r * ga + be);
        lds[(sc * 4 + 2) * 520 + c] = f2bf((v.z - m) * r * ga + be);
        lds[(sc * 4 + 3) * 520 + c] = f2bf((v.w - m) * r * ga + be);
    }
    __syncthreads();
#pragma unroll
    for (int i = 0; i < 8; ++i) {
        int p = t + 256 * i;
        int s = p >> 6, j = p & 63;
        float4 v = *reinterpret_cast<const float4*>(&lds[s * 520 + j * 8]);
        *reinterpret_cast<float4*>(
            hn + ((long long)(b * 1024 + s0 + s)) * 512 + j * 8) = v;
    }
}

// ---------------------------------------------------------------------------
// NT GEMM, 256x256 tile (AI = 64 FLOP/staged-byte, 2x the 128^2 tile),
// BK=64, 512 threads = 8 waves (2Mx4N, each wave owns 128x64 output),
// double-buffered 128KB LDS, counted-vmcnt pipeline (R4-proven skeleton):
//   iter kt: STAGE(kt+1 -> buf^1) ; vmcnt(8) (tile kt landed, kt+1's 8
//   loads stay in flight across the barrier) ; barrier ; COMPUTE ; barrier.
// Both-sides XOR swizzle (rule 21): global source col-chunk pre-swizzled
// (chunk ^ (row&7)), ds_read applies the same XOR -> conflict-free (R4: 0).
// C[m,n] = f(sum_k A[m,k]*B[n,k] + biasM[m] + biasN[n]) with optional
// exp(v-8) (EXPOUT), row divide (DIVROW), fp32 residual add (RESID).
// ---------------------------------------------------------------------------
template<int BIAS_M, int BIAS_N, int RESID, int EXPOUT, int DIVROW>
__global__ __launch_bounds__(512, 2)
void nt_gemm(const short* __restrict__ A, const short* __restrict__ B,
             void* __restrict__ Cv,
             const float* __restrict__ biasM, const float* __restrict__ biasN,
             const float* __restrict__ resid, const float* __restrict__ rs,
             int rsM, float scale, int K, int lda, int ldb, int ldc,
             long long sA, long long sB, long long sC,
             int tilesM, int tilesPerBatch)
{
    __shared__ short lsA[2][256 * 64];   // 2 x 32 KB
    __shared__ short lsB[2][256 * 64];   // 2 x 32 KB  (128 KB total)

    const int id = blockIdx.x;
    const int chunk = gridDim.x >> 3;    // grid % 8 == 0 by construction
    const int gid = (id & 7) * chunk + (id >> 3);
    const int bz = gid / tilesPerBatch;
    const int tt = gid - bz * tilesPerBatch;
    const int m0 = (tt % tilesM) * 256;
    const int n0 = (tt / tilesM) * 256;

    const int t = threadIdx.x;           // 0..511
    const int lane = t & 63;
    const int w = t >> 6;                // 0..7
    const int wm = w >> 2, wn = w & 3;   // wave tile: rows wm*128, cols wn*64
    const int lr16 = lane & 15, lkg = lane >> 4;
    const int sw = lr16 & 7;             // read-side swizzle key (row & 7)

    // staging: thread t, load j in 0..3 per operand:
    //   row = (t>>3) + 64j, global col chunk = (t&7) ^ ((t>>3)&7) (swizzled),
    //   LDS dest = linear t*16B + j*8KB  (wave-uniform base + lane*16 ✓)
    const int srow = t >> 3;
    const int scol = ((t & 7) ^ ((t >> 3) & 7)) * 8;
    const short* gA = A + (long long)bz * sA + (long long)(m0 + srow) * lda + scol;
    const short* gB = B + (long long)bz * sB + (long long)(n0 + srow) * ldb + scol;

    f32x4 acc[8][4];
#pragma unroll
    for (int i = 0; i < 8; ++i)
#pragma unroll
        for (int j = 0; j < 4; ++j) acc[i][j] = (f32x4){0.f, 0.f, 0.f, 0.f};

    const int nk = K >> 6;

#define STAGE(buf, kt)                                                         \
    {                                                                          \
        const short* ga_ = gA + (kt) * 64;                                     \
        const short* gb_ = gB + (kt) * 64;                                     \
        _Pragma("unroll")                                                      \
        for (int c = 0; c < 4; ++c) {                                          \
            __builtin_amdgcn_global_load_lds(                                  \
                (guint*)(ga_ + (long long)(64 * c) * lda),                     \
                (luint*)&lsA[buf][t * 8 + 4096 * c], 16, 0, 0);                \
            __builtin_amdgcn_global_load_lds(                                  \
                (guint*)(gb_ + (long long)(64 * c) * ldb),                     \
                (luint*)&lsB[buf][t * 8 + 4096 * c], 16, 0, 0);                \
        }                                                                      \
    }

#define COMPUTE(buf)                                                           \
    {                                                                          \
        _Pragma("unroll")                                                      \
        for (int ks = 0; ks < 2; ++ks) {                                       \
            bf16x8 bq[4];                                                      \
            _Pragma("unroll")                                                  \
            for (int ni = 0; ni < 4; ++ni)                                     \
                bq[ni] = *reinterpret_cast<const bf16x8*>(                     \
                    &lsB[buf][(wn * 64 + ni * 16 + lr16) * 64 +                \
                              (((ks * 4 + lkg) ^ sw) * 8)]);                   \
            _Pragma("unroll")                                                  \
            for (int mq = 0; mq < 4; ++mq) {                                   \
                bf16x8 aq[2];                                                  \
                _Pragma("unroll")                                              \
                for (int z = 0; z < 2; ++z)                                    \
                    aq[z] = *reinterpret_cast<const bf16x8*>(                  \
                        &lsA[buf][(wm * 128 + (mq * 2 + z) * 16 + lr16) * 64 + \
                                  (((ks * 4 + lkg) ^ sw) * 8)]);               \
                __builtin_amdgcn_s_setprio(1);                                 \
                _Pragma("unroll")                                              \
                for (int z = 0; z < 2; ++z)                                    \
                    _Pragma("unroll")                                          \
                    for (int ni = 0; ni < 4; ++ni)                             \
                        acc[mq * 2 + z][ni] =                                  \
                            __builtin_amdgcn_mfma_f32_16x16x32_bf16(           \
                                aq[z], bq[ni], acc[mq * 2 + z][ni], 0, 0, 0);  \
                __builtin_amdgcn_s_setprio(0);                                 \
            }                                                                  \
        }                                                                      \
    }

    STAGE(0, 0);
    int cur = 0;
    for (int kt = 0; kt < nk - 1; ++kt) {
        STAGE(cur ^ 1, kt + 1);
        asm volatile("s_waitcnt vmcnt(8)" ::: "memory");  // tile kt landed; kt+1 in flight
        __builtin_amdgcn_sched_barrier(0);
        __builtin_amdgcn_s_barrier();
        __builtin_amdgcn_sched_barrier(0);
        COMPUTE(cur);
        __builtin_amdgcn_sched_barrier(0);
        __builtin_amdgcn_s_barrier();                     // reads done before overwrite
        __builtin_amdgcn_sched_barrier(0);
        cur ^= 1;
    }
    asm volatile("s_waitcnt vmcnt(0)" ::: "memory");      // drain last tile
    __builtin_amdgcn_sched_barrier(0);
    __builtin_amdgcn_s_barrier();
    __builtin_amdgcn_sched_barrier(0);
    COMPUTE(cur);
#undef STAGE
#undef COMPUTE

    // epilogue: D layout col=lane&15, row=(lane>>4)*4+reg (m89-verified)
#pragma unroll
    for (int mi = 0; mi < 8; ++mi) {
        float addm[4], mul[4];
#pragma unroll
        for (int j = 0; j < 4; ++j) {
            const int rrow = m0 + wm * 128 + mi * 16 + lkg * 4 + j;
            addm[j] = BIAS_M ? biasM[rrow] : 0.f;
            mul[j]  = DIVROW ? 1.f / rs[(long long)bz * rsM + rrow] : 1.f;
        }
#pragma unroll
        for (int ni = 0; ni < 4; ++ni) {
            const int col = n0 + wn * 64 + ni * 16 + lr16;
            float bn = BIAS_N ? biasN[col] : 0.f;
#pragma unroll
            for (int j = 0; j < 4; ++j) {
                const int rrow = m0 + wm * 128 + mi * 16 + lkg * 4 + j;
                float v2 = acc[mi][ni][j] + addm[j] + bn;
                v2 *= scale;
                if (EXPOUT) v2 = __expf(v2 - 8.f);
                if (DIVROW) v2 *= mul[j];
                const long long idx = (long long)rrow * ldc + col;
                if (RESID) {
                    float* Cf = (float*)Cv + (long long)bz * sC;
                    Cf[idx] = v2 + resid[(long long)bz * sC + idx];
                } else {
                    short* Cs = (short*)Cv + (long long)bz * sC;
                    Cs[idx] = f2bf(v2);
                }
            }
        }
    }
}

// ---------------------------------------------------------------------------
// Row sums of expS (bf16, rows of 1024): one wave per row.
// ---------------------------------------------------------------------------
__global__ __launch_bounds__(256)
void rowsum_rows(const short* __restrict__ S, float* __restrict__ rs)
{
    const int wave = threadIdx.x >> 6, lane = threadIdx.x & 63;
    const long long row = (long long)blockIdx.x * 4 + wave;
    const short* p = S + row * 1024;
    bf16x8 h0 = *reinterpret_cast<const bf16x8*>(p + lane * 8);
    bf16x8 h1 = *reinterpret_cast<const bf16x8*>(p + 512 + lane * 8);
    float s = 0.f;
#pragma unroll
    for (int j = 0; j < 8; ++j) s += bf2f(h0[j]) + bf2f(h1[j]);
#pragma unroll
    for (int o = 32; o > 0; o >>= 1) s += __shfl_xor(s, o);
    if (lane == 0) rs[row] = s;
}

// ---------------------------------------------------------------------------
extern "C" void kernel_launch(void* const* d_in, const int* in_sizes, int n_in,
                              void* d_out, int out_size, void* d_ws, size_t ws_size,
                              hipStream_t stream)
{
    (void)in_sizes; (void)n_in; (void)out_size; (void)ws_size;
    const float* x     = (const float*)d_in[0];
    const float* gamma = (const float*)d_in[1];
    const float* beta  = (const float*)d_in[2];
    const float* Wq = (const float*)d_in[3];
    const float* bq = (const float*)d_in[4];
    const float* Wk = (const float*)d_in[5];
    const float* bk = (const float*)d_in[6];
    const float* Wv = (const float*)d_in[7];
    const float* bv = (const float*)d_in[8];
    const float* Wp = (const float*)d_in[9];
    const float* bp = (const float*)d_in[10];
    float* out = (float*)d_out;

    // Workspace (time-overlapped), ~162.2 MB:
    //   [0,64M):    expS (b,s,t) bf16; hn (b,s,c) bf16 in [0,32M) dies after
    //               the v-GEMM, before scores writes expS.
    //   [64,128M):  qk (b,s,1024) bf16; dies after scores; ho reuses [64,96M).
    //   [128,160M): v (b,c,t) bf16
    //   [160,162M): WT = {WqT*qs, WkT, WvT, WpT} (d,c) bf16
    //   [162M..):   stats (8K) | bqk (4K) | rs (128K)
    char* ws = (char*)d_ws;
    short*  expS = (short*)ws;
    short*  hn   = (short*)ws;
    short*  qkb  = (short*)(ws + (64LL << 20));
    short*  vbuf = (short*)(ws + (128LL << 20));
    short*  wT   = (short*)(ws + (160LL << 20));
    float2* stats = (float2*)(ws + (162LL << 20));
    float*  bqk   = (float*)(ws + (162LL << 20) + (16 << 10));
    float*  rs    = (float*)(ws + (162LL << 20) + (32 << 10));
    short*  ho    = qkb;

    const short* WqkT = wT;                  // rows 0-511: Wq^T*qs; 512-1023: Wk^T
    const short* WvT  = wT + 2 * 512 * 512;
    const short* WpT  = wT + 3 * 512 * 512;

    const float qscale = 0.044194173824159216f;  // 512^-0.5

    transpose_w<<<dim3(16, 16, 4), 256, 0, stream>>>(Wq, Wk, Wv, Wp, wT, qscale);
    concat_bias<<<dim3(4), 256, 0, stream>>>(bq, bk, bqk, qscale);
    gn_stats<<<dim3(1024), 256, 0, stream>>>(x, stats);
    gn_apply_t<<<dim3(32, 32), 256, 0, stream>>>(x, stats, gamma, beta, hn);

    // qk = hn @ [Wq*qs | Wk] + bqk : M=1024(s), N=1024(d'), K=512 -> 4x4x32
    nt_gemm<0, 1, 0, 0, 0><<<512, 512, 0, stream>>>(
        hn, WqkT, qkb, nullptr, bqk, nullptr, nullptr, 0, 1.f,
        512, 512, 512, 1024, 1024 * 512, 0, 1024LL * 1024, 4, 16);
    // v (d,t) = WvT @ hn^T + bv : M=512(d), N=1024(t), K=512 -> 2x4x32
    nt_gemm<1, 0, 0, 0, 0><<<256, 512, 0, stream>>>(
        WvT, hn, vbuf, bv, nullptr, nullptr, nullptr, 0, 1.f,
        512, 512, 512, 1024, 0, 1024 * 512, 512 * 1024, 2, 8);
    // expS (s,t) = exp(q @ k^T - 8) : M=N=1024, K=512 (qscale folded into q)
    nt_gemm<0, 0, 0, 1, 0><<<512, 512, 0, stream>>>(
        qkb, qkb + 512, expS, nullptr, nullptr, nullptr, nullptr, 0, 1.f,
        512, 1024, 1024, 1024, 1024LL * 1024, 1024LL * 1024, 1024LL * 1024, 4, 16);
    // rs[row] = sum_t expS
    rowsum_rows<<<dim3(8192), 256, 0, stream>>>(expS, rs);
    // ho (s,c) = (expS @ v^T) / rs : M=1024(s), N=512(c), K=1024 -> 4x2x32
    nt_gemm<0, 0, 0, 0, 1><<<256, 512, 0, stream>>>(
        expS, vbuf, ho, nullptr, nullptr, nullptr, rs, 1024, 1.f,
        1024, 1024, 1024, 512, 1024LL * 1024, 512 * 1024, 1024 * 512, 4, 8);
    // out (d,s) = WpT @ ho^T + bp + x : M=512(d), N=1024(s), K=512, fp32
    nt_gemm<1, 0, 1, 0, 0><<<256, 512, 0, stream>>>(
        WpT, ho, out, bp, nullptr, x, nullptr, 0, 1.f,
        512, 512, 512, 1024, 0, 1024 * 512, 512LL * 1024, 2, 8);
}